// Round 1
// baseline (184.470 us; speedup 1.0000x reference)
//
#include <hip/hip_runtime.h>
#include <hip/hip_bf16.h>
#include <stdint.h>

// SoftSplit = unfold(3x3, pad 1) + linear == 3x3 same-conv, Cin=64 -> Cout=96,
// channels-last fp32 output (8, 16384, 96). Implicit GEMM with bf16 MFMA.
// K reordered as k' = (ki*3+kj)*64 + cin so each 32-chunk = one tap x 32 ch.

typedef __bf16 bf16t;
typedef __bf16 bf16x8 __attribute__((ext_vector_type(8)));
typedef float  f32x4  __attribute__((ext_vector_type(4)));

#define CIN   64
#define COUT  96
#define HH    128
#define WW    128
#define KTOT  576            // CIN*9
#define NCH   18             // 9 taps * 2 channel-halves
#define BK    32
#define ASTR  40             // As row stride (bf16): 32 + 8 pad, 80 B (16B-aligned rows)

// Pre-kernel: W (96 x 576 fp32, k = cin*9 + r) -> Wp[ch][n][cc] bf16 (chunk-major)
__global__ void prep_w_kernel(const float* __restrict__ W, bf16t* __restrict__ Wp) {
    int idx = blockIdx.x * 256 + threadIdx.x;
    if (idx >= NCH * COUT * BK) return;
    int ch  = idx / (COUT * BK);
    int rem = idx - ch * (COUT * BK);
    int n   = rem >> 5;
    int cc  = rem & 31;
    int r    = ch >> 1;          // tap index ki*3+kj
    int half = ch & 1;
    int cin  = half * 32 + cc;
    Wp[idx] = (bf16t)W[n * KTOT + cin * 9 + r];
}

__global__ __launch_bounds__(256, 4) void conv_mfma_kernel(
    const float* __restrict__ x,
    const bf16t* __restrict__ Wp,
    const float* __restrict__ bias,
    float* __restrict__ out)
{
    __shared__ bf16t As[128 * ASTR];   // 10240 B
    __shared__ bf16t Bs[COUT * BK];    //  6144 B

    const int tid  = threadIdx.x;
    const int lane = tid & 63;
    const int wave = tid >> 6;
    const int lrow = lane & 15;
    const int quad = lane >> 4;

    const int b  = blockIdx.x >> 7;    // batch
    const int oi = blockIdx.x & 127;   // output image row

    // A-staging coords: thread loads 16 channels for one pixel column
    const int jm  = tid & 127;          // pixel column (M index)
    const int cc0 = (tid >> 7) << 4;    // 0 or 16 (channel sub-block)

    f32x4 acc[2][6];
    #pragma unroll
    for (int mt = 0; mt < 2; ++mt)
        #pragma unroll
        for (int nt = 0; nt < 6; ++nt)
            acc[mt][nt] = (f32x4){0.f, 0.f, 0.f, 0.f};

    const float* xb = x + (size_t)b * CIN * HH * WW;

    for (int ch = 0; ch < NCH; ++ch) {
        const int r    = ch >> 1;
        const int half = ch & 1;
        const int ki = r / 3;
        const int kj = r - ki * 3;
        const int ii = oi + ki - 1;
        const int jj = jm + kj - 1;
        const bool valid = ((unsigned)ii < 128u) && ((unsigned)jj < 128u);
        const float* srcp = xb + (((size_t)(half * 32 + cc0) * HH + ii) * WW + jj);

        float v[16];
        #pragma unroll
        for (int u = 0; u < 16; ++u)
            v[u] = valid ? srcp[(size_t)u * HH * WW] : 0.0f;

        bf16x8 p0, p1;
        #pragma unroll
        for (int u = 0; u < 8; ++u) { p0[u] = (bf16t)v[u]; p1[u] = (bf16t)v[u + 8]; }

        __syncthreads();   // previous chunk's fragment reads done before overwrite
        *reinterpret_cast<bf16x8*>(&As[jm * ASTR + cc0])     = p0;
        *reinterpret_cast<bf16x8*>(&As[jm * ASTR + cc0 + 8]) = p1;

        // B tile: contiguous 6144 B copy (L2-hot, shared by all blocks)
        const uint4* bsrc = reinterpret_cast<const uint4*>(Wp + (size_t)ch * COUT * BK);
        for (int t2 = tid; t2 < (COUT * BK) / 8; t2 += 256)   // 384 x uint4
            reinterpret_cast<uint4*>(Bs)[t2] = bsrc[t2];
        __syncthreads();

        // Fragments: A[m][k] m=lane&15 (+tile offsets), k=quad*8+j ; B from W[n][k]
        bf16x8 a0 = *reinterpret_cast<const bf16x8*>(&As[(wave * 32 + lrow) * ASTR + quad * 8]);
        bf16x8 a1 = *reinterpret_cast<const bf16x8*>(&As[(wave * 32 + 16 + lrow) * ASTR + quad * 8]);
        #pragma unroll
        for (int nt = 0; nt < 6; ++nt) {
            bf16x8 bf = *reinterpret_cast<const bf16x8*>(&Bs[(nt * 16 + lrow) * BK + quad * 8]);
            acc[0][nt] = __builtin_amdgcn_mfma_f32_16x16x32_bf16(a0, bf, acc[0][nt], 0, 0, 0);
            acc[1][nt] = __builtin_amdgcn_mfma_f32_16x16x32_bf16(a1, bf, acc[1][nt], 0, 0, 0);
        }
    }

    // Epilogue: D col=lane&15 (c2), row=quad*4+reg (pixel); add bias, fp32 store.
    float bv[6];
    #pragma unroll
    for (int nt = 0; nt < 6; ++nt) bv[nt] = bias[nt * 16 + lrow];

    float* outp = out + (size_t)blockIdx.x * 128 * COUT;
    #pragma unroll
    for (int mt = 0; mt < 2; ++mt) {
        const int prow = wave * 32 + mt * 16 + quad * 4;
        #pragma unroll
        for (int rg = 0; rg < 4; ++rg) {
            float* rowp = outp + (size_t)(prow + rg) * COUT;
            #pragma unroll
            for (int nt = 0; nt < 6; ++nt)
                rowp[nt * 16 + lrow] = acc[mt][nt][rg] + bv[nt];
        }
    }
}

extern "C" void kernel_launch(void* const* d_in, const int* in_sizes, int n_in,
                              void* d_out, int out_size, void* d_ws, size_t ws_size,
                              hipStream_t stream) {
    const float* x    = (const float*)d_in[0];   // (8,64,128,128)
    const float* W    = (const float*)d_in[1];   // (96,576)
    const float* bias = (const float*)d_in[2];   // (96,)
    float* out = (float*)d_out;                  // (8,16384,96)
    bf16t* Wp  = (bf16t*)d_ws;                   // 110592 B scratch

    hipLaunchKernelGGL(prep_w_kernel, dim3((NCH * COUT * BK + 255) / 256), dim3(256), 0, stream,
                       W, Wp);
    hipLaunchKernelGGL(conv_mfma_kernel, dim3(8 * HH), dim3(256), 0, stream,
                       x, Wp, bias, out);
}

// Round 2
// 115.641 us; speedup vs baseline: 1.5952x; 1.5952x over previous
//
#include <hip/hip_runtime.h>
#include <hip/hip_bf16.h>
#include <stdint.h>

// SoftSplit = unfold(3x3,pad1) + linear == 3x3 same-conv Cin=64 -> Cout=96,
// out (8,16384,96) fp32. Implicit GEMM, bf16 MFMA 16x16x32.
// Round 2: stage-once / barrier-free K-loop.
//  - block = 256 thr = one output row (M=128), LDS holds 3 input rows x 64ch
//    as bf16 NHWC with XOR-swizzled 16B blocks (transpose-friendly writes,
//    b128-floor fragment reads). ONE barrier pair per block, none in K-loop.
//  - B fragments read per-chunk from prepacked Wp (110 KB, L2-resident).
//  - XCD swizzle: blockIdx&7 = batch -> each XCD streams one batch (4.2 MB),
//    adjacent rows adjacent in launch order -> 3x row reuse caught in L2.

typedef __bf16 bf16t;
typedef __bf16 bf16x8 __attribute__((ext_vector_type(8)));
typedef float  f32x4  __attribute__((ext_vector_type(4)));

#define CIN   64
#define COUT  96
#define HH    128
#define WW    128
#define KTOT  576
#define NCH   18

#define XROW_DW (130 * 32)        // dwords per input-row slab (130 px * 32 dw)
#define XTOT_DW (3 * XROW_DW)     // 12480 dw = 49920 B LDS -> 3 blocks/CU

// Pre-kernel: W (96 x 576 fp32, k = cin*9 + r) -> Wp[ch][n][cc] bf16, ch = r*2+half
__global__ void prep_w_kernel(const float* __restrict__ W, bf16t* __restrict__ Wp) {
    int idx = blockIdx.x * 256 + threadIdx.x;
    if (idx >= NCH * COUT * 32) return;
    int ch  = idx / (COUT * 32);
    int rem = idx - ch * (COUT * 32);
    int n   = rem >> 5;
    int cc  = rem & 31;
    int r = ch >> 1, half = ch & 1;
    Wp[idx] = (bf16t)W[n * KTOT + (half * 32 + cc) * 9 + r];
}

// swizzle of the 4-dword block index within a pixel's 32-dword channel row;
// spreads both the transpose writes and the quad-strided fragment reads.
__device__ __forceinline__ int swz(int p) { return ((p >> 2) & 7) ^ ((p & 3) << 1); }

__device__ __forceinline__ uint32_t pack2(float lo, float hi) {
    uint16_t a = __builtin_bit_cast(uint16_t, (__bf16)lo);
    uint16_t b = __builtin_bit_cast(uint16_t, (__bf16)hi);
    return ((uint32_t)b << 16) | (uint32_t)a;
}

__global__ __launch_bounds__(256, 3) void conv_mfma_kernel(
    const float* __restrict__ x, const bf16t* __restrict__ Wp,
    const float* __restrict__ bias, float* __restrict__ out)
{
    __shared__ uint32_t Xs[XTOT_DW];

    const int tid  = threadIdx.x;
    const int lane = tid & 63;
    const int wave = tid >> 6;
    const int lrow = lane & 15;
    const int quad = lane >> 4;
    const int wm   = wave & 1;     // m-group: pixels wm*64 .. +63 (4 m-tiles)
    const int wn   = wave >> 1;    // n-group: cols wn*48 .. +47 (3 n-tiles)

    const int bb = blockIdx.x & 7;    // batch -> XCD-local
    const int oi = blockIdx.x >> 3;   // output row 0..127

    // ---- zero LDS (halo cols p=0/129 and out-of-range rows must be 0) ----
    uint4* X4 = (uint4*)Xs;
    #pragma unroll
    for (int i = 0; i < 13; ++i) {
        int idx = tid + 256 * i;
        if (idx < XTOT_DW / 4) X4[idx] = (uint4){0u, 0u, 0u, 0u};
    }
    __syncthreads();

    // ---- stage 3 input rows: NCHW fp32 -> swizzled NHWC bf16 ----
    const float* xb = x + (size_t)bb * CIN * HH * WW;
    #pragma unroll
    for (int it = 0; it < 12; ++it) {
        int g  = tid + 256 * it;       // 0..3071 = 3 rows * 32 chpairs * 32 jgroups
        int j0 = (g & 31) * 4;
        int cp = (g >> 5) & 31;        // channel pair
        int rh = g >> 10;              // 0..2
        int ii = oi - 1 + rh;
        if ((unsigned)ii < (unsigned)HH) {
            const float* s0 = xb + ((size_t)(2 * cp) * HH + ii) * WW + j0;
            float4 v0 = *(const float4*)s0;
            float4 v1 = *(const float4*)(s0 + HH * WW);
            float e0[4] = {v0.x, v0.y, v0.z, v0.w};
            float e1[4] = {v1.x, v1.y, v1.z, v1.w};
            #pragma unroll
            for (int u = 0; u < 4; ++u) {
                int p   = 1 + j0 + u;
                int cdw = (cp & 3) | ((((cp >> 2) ^ swz(p)) & 7) << 2);
                Xs[rh * XROW_DW + p * 32 + cdw] = pack2(e0[u], e1[u]);
            }
        }
    }
    __syncthreads();

    // ---- barrier-free K-loop: 18 chunks = 9 taps x 2 channel-halves ----
    f32x4 acc[4][3];
    #pragma unroll
    for (int a = 0; a < 4; ++a)
        #pragma unroll
        for (int nt = 0; nt < 3; ++nt)
            acc[a][nt] = (f32x4){0.f, 0.f, 0.f, 0.f};

    int pcol[4];
    #pragma unroll
    for (int a = 0; a < 4; ++a) pcol[a] = wm * 64 + a * 16 + lrow;

    const bf16t* wp_n = Wp + ((size_t)(wn * 48 + lrow)) * 32 + quad * 8;

    for (int r = 0; r < 9; ++r) {
        const int ki = r / 3, kj = r % 3;
        #pragma unroll
        for (int half = 0; half < 2; ++half) {
            const int ch = r * 2 + half;
            bf16x8 bfr[3];
            #pragma unroll
            for (int nt = 0; nt < 3; ++nt)
                bfr[nt] = *(const bf16x8*)(wp_n + (size_t)ch * COUT * 32 + nt * 16 * 32);
            bf16x8 afr[4];
            #pragma unroll
            for (int a = 0; a < 4; ++a) {
                int p   = pcol[a] + kj;
                int blk = (half * 4 + quad) ^ swz(p);
                afr[a] = *(const bf16x8*)&Xs[ki * XROW_DW + p * 32 + blk * 4];
            }
            #pragma unroll
            for (int a = 0; a < 4; ++a)
                #pragma unroll
                for (int nt = 0; nt < 3; ++nt)
                    acc[a][nt] = __builtin_amdgcn_mfma_f32_16x16x32_bf16(
                        afr[a], bfr[nt], acc[a][nt], 0, 0, 0);
        }
    }

    // ---- epilogue: D col=lane&15 (c2), row=quad*4+reg (pixel) ----
    float bv[3];
    #pragma unroll
    for (int nt = 0; nt < 3; ++nt) bv[nt] = bias[wn * 48 + nt * 16 + lrow];

    float* outp = out + ((size_t)bb * 16384 + (size_t)oi * 128) * COUT;
    #pragma unroll
    for (int a = 0; a < 4; ++a) {
        #pragma unroll
        for (int rg = 0; rg < 4; ++rg) {
            int m = wm * 64 + a * 16 + quad * 4 + rg;
            float* rowp = outp + (size_t)m * COUT + wn * 48;
            #pragma unroll
            for (int nt = 0; nt < 3; ++nt)
                rowp[nt * 16 + lrow] = acc[a][nt][rg] + bv[nt];
        }
    }
}

extern "C" void kernel_launch(void* const* d_in, const int* in_sizes, int n_in,
                              void* d_out, int out_size, void* d_ws, size_t ws_size,
                              hipStream_t stream) {
    const float* x    = (const float*)d_in[0];   // (8,64,128,128)
    const float* W    = (const float*)d_in[1];   // (96,576)
    const float* bias = (const float*)d_in[2];   // (96,)
    float* out = (float*)d_out;                  // (8,16384,96)
    bf16t* Wp  = (bf16t*)d_ws;                   // 110592 B scratch

    hipLaunchKernelGGL(prep_w_kernel, dim3((NCH * COUT * 32 + 255) / 256), dim3(256), 0, stream,
                       W, Wp);
    hipLaunchKernelGGL(conv_mfma_kernel, dim3(8 * HH), dim3(256), 0, stream,
                       x, Wp, bias, out);
}